// Round 1
// baseline (227.978 us; speedup 1.0000x reference)
//
#include <hip/hip_runtime.h>
#include <stdint.h>

// Causal GQA attention fwd, B=2 T=2048 H=32 HKV=8 D=128, fp32 in/out, bf16 MFMA compute.
//
// Pipeline:
//   cvt_k:  K fp32 [B,T,8,128] -> Kb bf16 [B,8,T,128], 16B-slot s stored at s^(t&7)
//           (pre-baked XOR swizzle so global_load_lds + linear LDS => conflict-free ds_read_b128)
//   cvt_v:  V fp32 [B,T,8,128] -> VTb bf16 tiled [B,8,tile(64)][d(128)][32 kv], slot s2 at s2^((d>>1)&3)
//   attn:   2048 blocks x 256 thr (4 waves). Block = (b, h, 64 q rows); wave = 16 q rows.
//           KV tiles of 32, double-buffered LDS staged via global_load_lds width=16.
//           QK^T swapped: S^T = mfma(K-frag, Q-frag)  (lane: q = lane&15, kv = (lane>>4)*4+reg)
//           Online softmax in log2 domain (Q pre-scaled by SCALING*log2e, exp2f).
//           P -> per-wave padded LDS (stride 40 ushorts, conflict-free) -> PV A-frag.
//           O = mfma(P-frag, V^T-frag): acc rows q=(lane>>4)*4+reg, col d=dt*16+(lane&15).

typedef __attribute__((ext_vector_type(8))) __bf16 bf16x8;
typedef __attribute__((ext_vector_type(4))) __bf16 bf16x4;
typedef __attribute__((ext_vector_type(4))) float f32x4;

#define QSCALE (0.08838834764831845f * 1.4426950408889634f)

// ---------------- pre-pass: K convert + swizzle ----------------
__global__ __launch_bounds__(256) void cvt_k(const float* __restrict__ k,
                                             unsigned short* __restrict__ kb) {
    unsigned tid = blockIdx.x * 256u + threadIdx.x;  // 19 bits total
    unsigned s = tid & 15u;            // 16B slot within 256B row
    unsigned h = (tid >> 4) & 7u;
    unsigned t = (tid >> 7) & 2047u;
    unsigned b = tid >> 18;
    const float4* src = (const float4*)(k + (size_t)tid * 8u);
    float4 f0 = src[0], f1 = src[1];
    bf16x8 r;
    r[0] = (__bf16)f0.x; r[1] = (__bf16)f0.y; r[2] = (__bf16)f0.z; r[3] = (__bf16)f0.w;
    r[4] = (__bf16)f1.x; r[5] = (__bf16)f1.y; r[6] = (__bf16)f1.z; r[7] = (__bf16)f1.w;
    size_t o = ((size_t)((b * 8u + h) * 2048u + t) * 16u + (s ^ (t & 7u))) * 8u;
    *(bf16x8*)(kb + o) = r;
}

// ---------------- pre-pass: V convert + transpose + tile ----------------
__global__ __launch_bounds__(256) void cvt_v(const float* __restrict__ v,
                                             unsigned short* __restrict__ vtb) {
    unsigned tid = blockIdx.x * 256u + threadIdx.x;
    unsigned d = tid & 127u;           // fast-varying => coalesced reads
    unsigned u = (tid >> 7) & 255u;    // t-chunk of 8
    unsigned h = (tid >> 15) & 7u;
    unsigned b = tid >> 18;
    const float* src = v + ((size_t)(b * 2048u + u * 8u) * 8u + h) * 128u + d;
    bf16x8 r;
#pragma unroll
    for (int j = 0; j < 8; ++j) r[j] = (__bf16)src[(size_t)j * 1024u];
    unsigned tile = u >> 2, s2 = u & 3u;
    size_t o = (((size_t)((b * 8u + h) * 64u + tile) * 128u + d) * 4u
                + (s2 ^ ((d >> 1) & 3u))) * 8u;
    *(bf16x8*)(vtb + o) = r;
}

// ---------------- main attention kernel ----------------
__device__ inline void load16_lds(const void* g, void* l) {
    __builtin_amdgcn_global_load_lds(
        (__attribute__((address_space(1))) void*)(g),
        (__attribute__((address_space(3))) void*)(l), 16, 0, 0);
}

__global__ __launch_bounds__(256) void attn_fwd(const float* __restrict__ qg,
                                                const unsigned short* __restrict__ kb,
                                                const unsigned short* __restrict__ vtb,
                                                float* __restrict__ outg) {
    __shared__ __align__(16) unsigned short Klds[2][32 * 128];   // swizzled rows of 256B
    __shared__ __align__(16) unsigned short Vlds[2][128 * 32];   // V^T rows of 64B, swizzled
    __shared__ __align__(16) unsigned short Plds[4][16 * 40];    // per-wave P, pad 32->40

    // XCD-aware decode: all 128 blocks of one (b,kvh) land on one XCD; qtiles descending.
    int bid = blockIdx.x;
    int x = bid & 7, ii = bid >> 3;
    int g = x + 8 * (ii >> 7);        // kv-group 0..15
    int j = ii & 127;
    int b = g >> 3, kvh = g & 7;
    int h = kvh * 4 + (j >> 5);
    int qtile = 31 - (j & 31);
    int q0 = qtile * 64;

    int lane = threadIdx.x & 63;
    int w = threadIdx.x >> 6;
    int lq = lane & 15;               // mfma "l&15" index
    int gq = lane >> 4;               // mfma group

    const unsigned short* kTile = kb + (size_t)(b * 8 + kvh) * 2048u * 128u;
    const unsigned short* vTile = vtb + (size_t)(b * 8 + kvh) * 64u * 4096u;
    int nt = 2 * (qtile + 1);

    auto stage = [&](int t, int buf) {
        const char* ks = (const char*)(kTile + (size_t)t * 4096u);  // contiguous 8KB
        const char* vs = (const char*)(vTile + (size_t)t * 4096u);  // contiguous 8KB
#pragma unroll
        for (int c2 = 0; c2 < 2; ++c2) {
            int call = w * 2 + c2;    // 8 calls of 1KB each, split over 4 waves
            load16_lds(ks + call * 1024 + lane * 16, &Klds[buf][call * 512]);
            load16_lds(vs + call * 1024 + lane * 16, &Vlds[buf][call * 512]);
        }
    };

    stage(0, 0);  // issue early; latency hides under Q load/convert

    int qrow = q0 + w * 16 + lq;
    const float* qb = qg + ((size_t)(b * 2048 + qrow) * 32u + h) * 128u;
    bf16x8 qf[4];
#pragma unroll
    for (int c = 0; c < 4; ++c) {
        const float4* p4 = (const float4*)(qb + c * 32 + gq * 8);
        float4 f0 = p4[0], f1 = p4[1];
        qf[c][0] = (__bf16)(f0.x * QSCALE); qf[c][1] = (__bf16)(f0.y * QSCALE);
        qf[c][2] = (__bf16)(f0.z * QSCALE); qf[c][3] = (__bf16)(f0.w * QSCALE);
        qf[c][4] = (__bf16)(f1.x * QSCALE); qf[c][5] = (__bf16)(f1.y * QSCALE);
        qf[c][6] = (__bf16)(f1.z * QSCALE); qf[c][7] = (__bf16)(f1.w * QSCALE);
    }

    f32x4 zero4 = {0.f, 0.f, 0.f, 0.f};
    f32x4 acc[8];
#pragma unroll
    for (int dt = 0; dt < 8; ++dt) acc[dt] = zero4;
    float m_run = -1e30f, l_run = 0.f;
    int wqmax = q0 + w * 16 + 15;

    for (int t = 0; t < nt; ++t) {
        asm volatile("s_waitcnt vmcnt(0)" ::: "memory");  // stage(t) landed
        __syncthreads();                                  // + all waves done with buf^1
        int buf = t & 1;
        if (t + 1 < nt) stage(t + 1, buf ^ 1);            // stays in flight across compute
        int kv0 = t * 32;
        if (kv0 <= wqmax) {                               // wave-uniform causal skip
            // ---- QK^T (swapped): S^T tiles, lane: q=lq, kv=gq*4+reg (+16 for st1)
            f32x4 st0 = zero4, st1 = zero4;
#pragma unroll
            for (int c = 0; c < 4; ++c) {
                int kvl0 = lq;
                bf16x8 kf0 = *(const bf16x8*)&Klds[buf][kvl0 * 128 + (((c * 4 + gq) ^ (kvl0 & 7)) << 3)];
                st0 = __builtin_amdgcn_mfma_f32_16x16x32_bf16(kf0, qf[c], st0, 0, 0, 0);
                int kvl1 = 16 + lq;
                bf16x8 kf1 = *(const bf16x8*)&Klds[buf][kvl1 * 128 + (((c * 4 + gq) ^ (kvl1 & 7)) << 3)];
                st1 = __builtin_amdgcn_mfma_f32_16x16x32_bf16(kf1, qf[c], st1, 0, 0, 0);
            }
            // ---- causal mask + online softmax (log2 domain)
            float vals[8];
            float mx = -1e30f;
#pragma unroll
            for (int r = 0; r < 4; ++r) {
                float s0 = (kv0 + gq * 4 + r <= qrow) ? st0[r] : -1e30f;
                float s1 = (kv0 + 16 + gq * 4 + r <= qrow) ? st1[r] : -1e30f;
                vals[r] = s0; vals[4 + r] = s1;
                mx = fmaxf(mx, fmaxf(s0, s1));
            }
            mx = fmaxf(mx, __shfl_xor(mx, 16));
            mx = fmaxf(mx, __shfl_xor(mx, 32));
            float m_new = fmaxf(m_run, mx);
            float fac = exp2f(m_run - m_new);
            float ps = 0.f;
#pragma unroll
            for (int e = 0; e < 8; ++e) { vals[e] = exp2f(vals[e] - m_new); ps += vals[e]; }
            ps += __shfl_xor(ps, 16);
            ps += __shfl_xor(ps, 32);
            l_run = l_run * fac + ps;
            m_run = m_new;
            // ---- P -> per-wave LDS (bf16), then PV
            bf16x4 p0, p1;
#pragma unroll
            for (int r = 0; r < 4; ++r) { p0[r] = (__bf16)vals[r]; p1[r] = (__bf16)vals[4 + r]; }
            *(bf16x4*)&Plds[w][lq * 40 + gq * 4] = p0;
            *(bf16x4*)&Plds[w][lq * 40 + 16 + gq * 4] = p1;
            float fr[4];
#pragma unroll
            for (int r = 0; r < 4; ++r) fr[r] = __shfl(fac, gq * 4 + r);  // acc rows are q=gq*4+r
            bf16x8 pf = *(const bf16x8*)&Plds[w][lq * 40 + gq * 8];
#pragma unroll
            for (int dt = 0; dt < 8; ++dt) {
#pragma unroll
                for (int r = 0; r < 4; ++r) acc[dt][r] *= fr[r];
                int d = dt * 16 + lq;
                bf16x8 vf = *(const bf16x8*)&Vlds[buf][d * 32 + ((gq ^ ((d >> 1) & 3)) << 3)];
                acc[dt] = __builtin_amdgcn_mfma_f32_16x16x32_bf16(pf, vf, acc[dt], 0, 0, 0);
            }
        }
    }

    // ---- epilogue: divide by row sum, store fp32
    float il = 1.0f / l_run;
    float ilr[4];
#pragma unroll
    for (int r = 0; r < 4; ++r) ilr[r] = __shfl(il, gq * 4 + r);
    float* ob = outg + (size_t)(b * 2048 + q0 + w * 16) * 4096u + h * 128;
#pragma unroll
    for (int dt = 0; dt < 8; ++dt)
#pragma unroll
        for (int r = 0; r < 4; ++r)
            ob[(size_t)(gq * 4 + r) * 4096u + dt * 16 + lq] = acc[dt][r] * ilr[r];
}

extern "C" void kernel_launch(void* const* d_in, const int* in_sizes, int n_in,
                              void* d_out, int out_size, void* d_ws, size_t ws_size,
                              hipStream_t stream) {
    const float* q = (const float*)d_in[0];
    const float* k = (const float*)d_in[1];
    const float* v = (const float*)d_in[2];
    float* out = (float*)d_out;
    unsigned short* kbuf = (unsigned short*)d_ws;                    // 8 MB bf16 K
    unsigned short* vbuf = kbuf + (size_t)2 * 8 * 2048 * 128;        // 8 MB bf16 V^T (tiled)
    cvt_k<<<2048, 256, 0, stream>>>(k, kbuf);
    cvt_v<<<2048, 256, 0, stream>>>(v, vbuf);
    attn_fwd<<<2048, 256, 0, stream>>>(q, kbuf, vbuf, out);
}

// Round 2
// 189.464 us; speedup vs baseline: 1.2033x; 1.2033x over previous
//
#include <hip/hip_runtime.h>
#include <stdint.h>

// Causal GQA attention fwd, B=2 T=2048 H=32 HKV=8 D=128, fp32 in/out, bf16 MFMA compute.
//
// Round 2: Q=32 rows/wave (two 16-row subtiles sharing K/V fragments), 1024 blocks,
// defer-rescale (T13, THR=8 log2-domain), diagonal-only masking.
//
//   cvt_k:  K fp32 [B,T,8,128] -> Kb bf16 [B,8,T,128], 16B-slot s stored at s^(t&7)
//   cvt_v:  V fp32 [B,T,8,128] -> VTb bf16 tiled [B,8,tile(64)][d(128)][32 kv], slot s2 at s2^((d>>1)&3)
//   attn:   1024 blocks x 256 thr (4 waves). Block = (b, h, 128 q rows); wave = 32 q rows.
//           KV tiles of 32, double-buffered LDS staged via global_load_lds width=16.
//           QK^T swapped: S^T = mfma(K-frag, Q-frag)  (lane: q = lane&15, kv = (lane>>4)*4+reg)
//           Online softmax in log2 domain (Q pre-scaled by SCALING*log2e, exp2f).

typedef __attribute__((ext_vector_type(8))) __bf16 bf16x8;
typedef __attribute__((ext_vector_type(4))) __bf16 bf16x4;
typedef __attribute__((ext_vector_type(4))) float f32x4;

#define QSCALE (0.08838834764831845f * 1.4426950408889634f)

// ---------------- pre-pass: K convert + swizzle ----------------
__global__ __launch_bounds__(256) void cvt_k(const float* __restrict__ k,
                                             unsigned short* __restrict__ kb) {
    unsigned tid = blockIdx.x * 256u + threadIdx.x;
    unsigned s = tid & 15u;
    unsigned h = (tid >> 4) & 7u;
    unsigned t = (tid >> 7) & 2047u;
    unsigned b = tid >> 18;
    const float4* src = (const float4*)(k + (size_t)tid * 8u);
    float4 f0 = src[0], f1 = src[1];
    bf16x8 r;
    r[0] = (__bf16)f0.x; r[1] = (__bf16)f0.y; r[2] = (__bf16)f0.z; r[3] = (__bf16)f0.w;
    r[4] = (__bf16)f1.x; r[5] = (__bf16)f1.y; r[6] = (__bf16)f1.z; r[7] = (__bf16)f1.w;
    size_t o = ((size_t)((b * 8u + h) * 2048u + t) * 16u + (s ^ (t & 7u))) * 8u;
    *(bf16x8*)(kb + o) = r;
}

// ---------------- pre-pass: V convert + transpose + tile ----------------
__global__ __launch_bounds__(256) void cvt_v(const float* __restrict__ v,
                                             unsigned short* __restrict__ vtb) {
    unsigned tid = blockIdx.x * 256u + threadIdx.x;
    unsigned d = tid & 127u;
    unsigned u = (tid >> 7) & 255u;
    unsigned h = (tid >> 15) & 7u;
    unsigned b = tid >> 18;
    const float* src = v + ((size_t)(b * 2048u + u * 8u) * 8u + h) * 128u + d;
    bf16x8 r;
#pragma unroll
    for (int j = 0; j < 8; ++j) r[j] = (__bf16)src[(size_t)j * 1024u];
    unsigned tile = u >> 2, s2 = u & 3u;
    size_t o = (((size_t)((b * 8u + h) * 64u + tile) * 128u + d) * 4u
                + (s2 ^ ((d >> 1) & 3u))) * 8u;
    *(bf16x8*)(vtb + o) = r;
}

// ---------------- main attention kernel ----------------
__device__ inline void load16_lds(const void* g, void* l) {
    __builtin_amdgcn_global_load_lds(
        (__attribute__((address_space(1))) void*)(g),
        (__attribute__((address_space(3))) void*)(l), 16, 0, 0);
}

__global__ __launch_bounds__(256, 3) void attn_fwd(const float* __restrict__ qg,
                                                   const unsigned short* __restrict__ kb,
                                                   const unsigned short* __restrict__ vtb,
                                                   float* __restrict__ outg) {
    __shared__ __align__(16) unsigned short Klds[2][32 * 128];   // 16 KB
    __shared__ __align__(16) unsigned short Vlds[2][128 * 32];   // 16 KB
    __shared__ __align__(16) unsigned short Plds[4][32 * 40];    // 10 KB, pad 32->40

    // XCD-aware decode: 1024 blocks; the 64 blocks of one (b,kvh) land on one XCD.
    int bid = blockIdx.x;
    int x = bid & 7, ii = bid >> 3;            // ii: 0..127
    int g = x + 8 * (ii >> 6);                 // kv-group 0..15
    int j = ii & 63;
    int b = g >> 3, kvh = g & 7;
    int h = kvh * 4 + (j >> 4);
    int qtile = 15 - (j & 15);                 // descending: long blocks first
    int q0 = qtile * 128;

    int lane = threadIdx.x & 63;
    int w = threadIdx.x >> 6;
    int lq = lane & 15;
    int gq = lane >> 4;
    int qbase = q0 + w * 32;

    const unsigned short* kTile = kb + (size_t)(b * 8 + kvh) * 2048u * 128u;
    const unsigned short* vTile = vtb + (size_t)(b * 8 + kvh) * 64u * 4096u;
    int nt = 4 * (qtile + 1);

    auto stage = [&](int t, int buf) {
        const char* ks = (const char*)(kTile + (size_t)t * 4096u);
        const char* vs = (const char*)(vTile + (size_t)t * 4096u);
#pragma unroll
        for (int c2 = 0; c2 < 2; ++c2) {
            int call = w * 2 + c2;
            load16_lds(ks + call * 1024 + lane * 16, &Klds[buf][call * 512]);
            load16_lds(vs + call * 1024 + lane * 16, &Vlds[buf][call * 512]);
        }
    };

    stage(0, 0);

    bf16x8 qf[2][4];
#pragma unroll
    for (int half = 0; half < 2; ++half) {
        const float* qb = qg + ((size_t)(b * 2048 + qbase + half * 16 + lq) * 32u + h) * 128u;
#pragma unroll
        for (int c = 0; c < 4; ++c) {
            const float4* p4 = (const float4*)(qb + c * 32 + gq * 8);
            float4 f0 = p4[0], f1 = p4[1];
            qf[half][c][0] = (__bf16)(f0.x * QSCALE); qf[half][c][1] = (__bf16)(f0.y * QSCALE);
            qf[half][c][2] = (__bf16)(f0.z * QSCALE); qf[half][c][3] = (__bf16)(f0.w * QSCALE);
            qf[half][c][4] = (__bf16)(f1.x * QSCALE); qf[half][c][5] = (__bf16)(f1.y * QSCALE);
            qf[half][c][6] = (__bf16)(f1.z * QSCALE); qf[half][c][7] = (__bf16)(f1.w * QSCALE);
        }
    }

    f32x4 zero4 = {0.f, 0.f, 0.f, 0.f};
    f32x4 acc[2][8];
#pragma unroll
    for (int half = 0; half < 2; ++half)
#pragma unroll
        for (int dt = 0; dt < 8; ++dt) acc[half][dt] = zero4;
    float mrun[2] = {-1e30f, -1e30f}, lrun[2] = {0.f, 0.f};

    for (int t = 0; t < nt; ++t) {
        asm volatile("s_waitcnt vmcnt(0)" ::: "memory");
        __syncthreads();
        int buf = t & 1;
        if (t + 1 < nt) stage(t + 1, buf ^ 1);
        int kv0 = t * 32;
        if (kv0 <= qbase + 31) {                         // wave-uniform causal skip
            // ---- QK^T: K-frags shared by both q-halves
            f32x4 st[2][2];
            st[0][0] = zero4; st[0][1] = zero4; st[1][0] = zero4; st[1][1] = zero4;
            int soff = lq & 7;                           // (16+lq)&7 == lq&7
#pragma unroll
            for (int c = 0; c < 4; ++c) {
                bf16x8 kf0 = *(const bf16x8*)&Klds[buf][lq * 128 + (((c * 4 + gq) ^ soff) << 3)];
                bf16x8 kf1 = *(const bf16x8*)&Klds[buf][(16 + lq) * 128 + (((c * 4 + gq) ^ soff) << 3)];
                st[0][0] = __builtin_amdgcn_mfma_f32_16x16x32_bf16(kf0, qf[0][c], st[0][0], 0, 0, 0);
                st[1][0] = __builtin_amdgcn_mfma_f32_16x16x32_bf16(kf0, qf[1][c], st[1][0], 0, 0, 0);
                st[0][1] = __builtin_amdgcn_mfma_f32_16x16x32_bf16(kf1, qf[0][c], st[0][1], 0, 0, 0);
                st[1][1] = __builtin_amdgcn_mfma_f32_16x16x32_bf16(kf1, qf[1][c], st[1][1], 0, 0, 0);
            }
            // ---- mask (diagonal tiles only) + per-row max
            float vals[2][8], mx[2];
            bool need_mask = (kv0 + 31 > qbase);         // wave-uniform
#pragma unroll
            for (int half = 0; half < 2; ++half) {
                float m = -1e30f;
                if (need_mask) {
                    int qr = qbase + half * 16 + lq;
#pragma unroll
                    for (int r = 0; r < 4; ++r) {
                        float s0 = (kv0 + gq * 4 + r <= qr) ? st[half][0][r] : -1e30f;
                        float s1 = (kv0 + 16 + gq * 4 + r <= qr) ? st[half][1][r] : -1e30f;
                        vals[half][r] = s0; vals[half][4 + r] = s1;
                        m = fmaxf(m, fmaxf(s0, s1));
                    }
                } else {
#pragma unroll
                    for (int r = 0; r < 4; ++r) {
                        float s0 = st[half][0][r], s1 = st[half][1][r];
                        vals[half][r] = s0; vals[half][4 + r] = s1;
                        m = fmaxf(m, fmaxf(s0, s1));
                    }
                }
                m = fmaxf(m, __shfl_xor(m, 16));
                m = fmaxf(m, __shfl_xor(m, 32));
                mx[half] = m;
            }
            // ---- T13 defer-rescale: only rescale when max grew by > 8 (log2 domain)
            if (!__all(mx[0] <= mrun[0] + 8.f && mx[1] <= mrun[1] + 8.f)) {
#pragma unroll
                for (int half = 0; half < 2; ++half) {
                    float mn = fmaxf(mrun[half], mx[half]);
                    float fac = exp2f(mrun[half] - mn);
                    lrun[half] *= fac; mrun[half] = mn;
                    float fr0 = __shfl(fac, gq * 4);
                    float fr1 = __shfl(fac, gq * 4 + 1);
                    float fr2 = __shfl(fac, gq * 4 + 2);
                    float fr3 = __shfl(fac, gq * 4 + 3);
#pragma unroll
                    for (int dt = 0; dt < 8; ++dt) {
                        acc[half][dt][0] *= fr0; acc[half][dt][1] *= fr1;
                        acc[half][dt][2] *= fr2; acc[half][dt][3] *= fr3;
                    }
                }
            }
            // ---- exp2, row-sum, P -> per-wave LDS
#pragma unroll
            for (int half = 0; half < 2; ++half) {
                float ps = 0.f;
                bf16x4 p0, p1;
#pragma unroll
                for (int r = 0; r < 4; ++r) {
                    float v0 = exp2f(vals[half][r] - mrun[half]);
                    float v1 = exp2f(vals[half][4 + r] - mrun[half]);
                    ps += v0 + v1;
                    p0[r] = (__bf16)v0; p1[r] = (__bf16)v1;
                }
                ps += __shfl_xor(ps, 16);
                ps += __shfl_xor(ps, 32);
                lrun[half] += ps;
                *(bf16x4*)&Plds[w][(half * 16 + lq) * 40 + gq * 4] = p0;
                *(bf16x4*)&Plds[w][(half * 16 + lq) * 40 + 16 + gq * 4] = p1;
            }
            // ---- PV: V-frags shared by both q-halves
            bf16x8 pfA = *(const bf16x8*)&Plds[w][lq * 40 + gq * 8];
            bf16x8 pfB = *(const bf16x8*)&Plds[w][(16 + lq) * 40 + gq * 8];
#pragma unroll
            for (int dt = 0; dt < 8; ++dt) {
                int d = dt * 16 + lq;
                bf16x8 vf = *(const bf16x8*)&Vlds[buf][d * 32 + ((gq ^ ((d >> 1) & 3)) << 3)];
                acc[0][dt] = __builtin_amdgcn_mfma_f32_16x16x32_bf16(pfA, vf, acc[0][dt], 0, 0, 0);
                acc[1][dt] = __builtin_amdgcn_mfma_f32_16x16x32_bf16(pfB, vf, acc[1][dt], 0, 0, 0);
            }
        }
    }

    // ---- epilogue
#pragma unroll
    for (int half = 0; half < 2; ++half) {
        float il = 1.0f / lrun[half];
        float i0 = __shfl(il, gq * 4);
        float i1 = __shfl(il, gq * 4 + 1);
        float i2 = __shfl(il, gq * 4 + 2);
        float i3 = __shfl(il, gq * 4 + 3);
        float* ob = outg + (size_t)(b * 2048 + qbase + half * 16) * 4096u + h * 128;
#pragma unroll
        for (int dt = 0; dt < 8; ++dt) {
            ob[(size_t)(gq * 4 + 0) * 4096u + dt * 16 + lq] = acc[half][dt][0] * i0;
            ob[(size_t)(gq * 4 + 1) * 4096u + dt * 16 + lq] = acc[half][dt][1] * i1;
            ob[(size_t)(gq * 4 + 2) * 4096u + dt * 16 + lq] = acc[half][dt][2] * i2;
            ob[(size_t)(gq * 4 + 3) * 4096u + dt * 16 + lq] = acc[half][dt][3] * i3;
        }
    }
}

extern "C" void kernel_launch(void* const* d_in, const int* in_sizes, int n_in,
                              void* d_out, int out_size, void* d_ws, size_t ws_size,
                              hipStream_t stream) {
    const float* q = (const float*)d_in[0];
    const float* k = (const float*)d_in[1];
    const float* v = (const float*)d_in[2];
    float* out = (float*)d_out;
    unsigned short* kbuf = (unsigned short*)d_ws;                    // 8 MB bf16 K
    unsigned short* vbuf = kbuf + (size_t)2 * 8 * 2048 * 128;        // 8 MB bf16 V^T (tiled)
    cvt_k<<<2048, 256, 0, stream>>>(k, kbuf);
    cvt_v<<<2048, 256, 0, stream>>>(v, vbuf);
    attn_fwd<<<1024, 256, 0, stream>>>(q, kbuf, vbuf, out);
}